// Round 5
// baseline (289.548 us; speedup 1.0000x reference)
//
#include <hip/hip_runtime.h>
#include <hip/hip_cooperative_groups.h>
#include <math.h>

namespace cg = cooperative_groups;

#define EDGE_DIM 3
#define NUM_HEADS 8
#define HIDDEN 16

typedef float float4v __attribute__((ext_vector_type(4)));

// Per-edge tiny MLP: (3) -> (16) relu -> (8)
__device__ __forceinline__ void edge_mlp(const float a0, const float a1, const float a2,
                                         const float* __restrict__ W1,
                                         const float* __restrict__ b1,
                                         const float* __restrict__ W2,
                                         const float* __restrict__ b2,
                                         float* o /* [NUM_HEADS] */) {
    float h[HIDDEN];
#pragma unroll
    for (int j = 0; j < HIDDEN; ++j) {
        float s = b1[j];
        s += a0 * W1[0 * HIDDEN + j];
        s += a1 * W1[1 * HIDDEN + j];
        s += a2 * W1[2 * HIDDEN + j];
        h[j] = s > 0.0f ? s : 0.0f;
    }
#pragma unroll
    for (int i = 0; i < NUM_HEADS; ++i) {
        float s = b2[i];
#pragma unroll
        for (int j = 0; j < HIDDEN; ++j) s += h[j] * W2[j * NUM_HEADS + i];
        o[i] = s;
    }
}

// One cooperative kernel: zero -> mark -> winner-write, grid.sync() between
// phases (replaces 3 graph nodes with 1; kernel-boundary overhead was ~13 us
// of round 3's 33 us).
__global__ __launch_bounds__(256, 4) void k_fused(
        const int* __restrict__ ei, const float* __restrict__ ea,
        const float* __restrict__ W1, const float* __restrict__ b1,
        const float* __restrict__ W2, const float* __restrict__ b2,
        float* __restrict__ out, int E, int N, size_t n4) {
    cg::grid_group grid = cg::this_grid();
    const size_t T = (size_t)gridDim.x * blockDim.x;
    const size_t tid = (size_t)blockIdx.x * blockDim.x + threadIdx.x;

    // Phase 1: zero the dense output (134 MB) — coalesced float4 grid-stride.
    {
        float4v z = {0.0f, 0.0f, 0.0f, 0.0f};
        float4v* o4 = (float4v*)out;
        for (size_t i = tid; i < n4; i += T) o4[i] = z;
    }
    grid.sync();

    // Phase 2: deterministic winner per (src,dst) slot = max edge index
    // (matches np/JAX scatter last-write-wins). Marker (e+1) as uint in
    // word 0 of the zeroed slot.
    for (size_t e = tid; e < (size_t)E; e += T) {
        size_t slot = (size_t)ei[e] * (size_t)N + (size_t)ei[(size_t)E + e];
        atomicMax((unsigned*)(out + slot * NUM_HEADS), (unsigned)(e + 1));
    }
    grid.sync();

    // Phase 3: each edge re-reads the marker; only the winner computes the
    // MLP and writes all 8 words. Word-0 overwrite hazard: a losing duplicate
    // reading word 0 concurrently sees either the winner's marker (w+1 != its
    // own e+1) or the winner's final float, whose bit pattern is flushed away
    // from [1, E] (denormals < 1e-40 -> 0.0f) — both correctly lose.
    for (size_t e = tid; e < (size_t)E; e += T) {
        size_t slot = (size_t)ei[e] * (size_t)N + (size_t)ei[(size_t)E + e];
        float* p = out + slot * NUM_HEADS;
        unsigned m = *(volatile const unsigned*)p;
        if (m != (unsigned)(e + 1)) continue;  // not the winner
        float o[NUM_HEADS];
        edge_mlp(ea[e * EDGE_DIM + 0], ea[e * EDGE_DIM + 1], ea[e * EDGE_DIM + 2],
                 W1, b1, W2, b2, o);
        unsigned u = __float_as_uint(o[0]);
        if (u >= 1u && u <= (unsigned)E) o[0] = 0.0f;  // flush marker-aliasing denormals
        float4v lo = {o[0], o[1], o[2], o[3]};
        float4v hi = {o[4], o[5], o[6], o[7]};
        *(float4v*)p = lo;        // slot is 32B-aligned
        *(float4v*)(p + 4) = hi;
    }
}

// ---- Fallback path (round-3 structure, proven 33 us) ----
__global__ void k_mark_out(const int* __restrict__ ei, float* __restrict__ out,
                           int E, int N) {
    int e = blockIdx.x * blockDim.x + threadIdx.x;
    if (e >= E) return;
    size_t slot = (size_t)ei[e] * (size_t)N + (size_t)ei[E + e];
    atomicMax((unsigned*)(out + slot * NUM_HEADS), (unsigned)(e + 1));
}

__global__ void k_write_out(const int* __restrict__ ei, const float* __restrict__ ea,
                            const float* __restrict__ W1, const float* __restrict__ b1,
                            const float* __restrict__ W2, const float* __restrict__ b2,
                            float* __restrict__ out, int E, int N) {
    int e = blockIdx.x * blockDim.x + threadIdx.x;
    if (e >= E) return;
    size_t slot = (size_t)ei[e] * (size_t)N + (size_t)ei[E + e];
    float* p = out + slot * NUM_HEADS;
    unsigned m = *(const unsigned*)p;
    if (m != (unsigned)(e + 1)) return;
    float o[NUM_HEADS];
    edge_mlp(ea[e * EDGE_DIM + 0], ea[e * EDGE_DIM + 1], ea[e * EDGE_DIM + 2],
             W1, b1, W2, b2, o);
    unsigned u = __float_as_uint(o[0]);
    if (u >= 1u && u <= (unsigned)E) o[0] = 0.0f;
    float4v lo = {o[0], o[1], o[2], o[3]};
    float4v hi = {o[4], o[5], o[6], o[7]};
    *(float4v*)p = lo;
    *(float4v*)(p + 4) = hi;
}

extern "C" void kernel_launch(void* const* d_in, const int* in_sizes, int n_in,
                              void* d_out, int out_size, void* d_ws, size_t ws_size,
                              hipStream_t stream) {
    const int* ei   = (const int*)d_in[0];    // (2, E) int32
    const float* ea = (const float*)d_in[1];  // (E, 3) f32
    const float* W1 = (const float*)d_in[3];  // (3, 16)
    const float* b1 = (const float*)d_in[4];  // (16,)
    const float* W2 = (const float*)d_in[5];  // (16, 8)
    const float* b2 = (const float*)d_in[6];  // (8,)
    float* out = (float*)d_out;

    const int E = in_sizes[0] / 2;
    const int N = (int)(sqrt((double)(out_size / NUM_HEADS)) + 0.5);
    size_t n4 = (size_t)out_size / 4;

    // Single cooperative kernel: 1024 blocks x 256 threads = 4 blocks/CU
    // (guaranteed co-resident by __launch_bounds__(256,4)).
    void* args[] = {(void*)&ei, (void*)&ea, (void*)&W1, (void*)&b1,
                    (void*)&W2, (void*)&b2, (void*)&out,
                    (void*)&E, (void*)&N, (void*)&n4};
    hipError_t err = hipLaunchCooperativeKernel((const void*)k_fused,
                                                dim3(1024), dim3(256),
                                                args, 0, stream);
    if (err != hipSuccess) {
        // Fallback: proven 3-node round-3 path.
        hipMemsetAsync(d_out, 0, (size_t)out_size * sizeof(float), stream);
        const int blk = 256;
        const int grid = (E + blk - 1) / blk;
        k_mark_out<<<grid, blk, 0, stream>>>(ei, out, E, N);
        k_write_out<<<grid, blk, 0, stream>>>(ei, ea, W1, b1, W2, b2, out, E, N);
    }
}

// Round 7
// 67.124 us; speedup vs baseline: 4.3136x; 4.3136x over previous
//
#include <hip/hip_runtime.h>
#include <math.h>

#define EDGE_DIM 3
#define NUM_HEADS 8
#define HIDDEN 16
#define NBLK 256
#define TPB 256

typedef float float4v __attribute__((ext_vector_type(4)));

// Per-edge tiny MLP: (3) -> (16) relu -> (8)
__device__ __forceinline__ void edge_mlp(const float a0, const float a1, const float a2,
                                         const float* __restrict__ W1,
                                         const float* __restrict__ b1,
                                         const float* __restrict__ W2,
                                         const float* __restrict__ b2,
                                         float* o /* [NUM_HEADS] */) {
    float h[HIDDEN];
#pragma unroll
    for (int j = 0; j < HIDDEN; ++j) {
        float s = b1[j];
        s += a0 * W1[0 * HIDDEN + j];
        s += a1 * W1[1 * HIDDEN + j];
        s += a2 * W1[2 * HIDDEN + j];
        h[j] = s > 0.0f ? s : 0.0f;
    }
#pragma unroll
    for (int i = 0; i < NUM_HEADS; ++i) {
        float s = b2[i];
#pragma unroll
        for (int j = 0; j < HIDDEN; ++j) s += h[j] * W2[j * NUM_HEADS + i];
        o[i] = s;
    }
}

// DIY grid barrier for a co-resident 256-block grid (1 block/CU on 256 CUs).
// Arrival: release (__threadfence) + device-scope atomicAdd. Wait: device-
// scope atomic RMW read (punches through non-coherent per-XCD L2s, unlike a
// plain/volatile load) with s_sleep backoff so pollers don't saturate the
// counter line. NOT cg::grid_group::sync — that measured ~100 us/sync (r5).
__device__ __forceinline__ void grid_barrier(unsigned* cnt, unsigned target) {
    __syncthreads();
    if (threadIdx.x == 0) {
        __threadfence();                       // release prior writes
        atomicAdd(cnt, 1u);
        while (atomicAdd(cnt, 0u) < target) {  // device-coherent read
            __builtin_amdgcn_s_sleep(1);
        }
        __threadfence();                       // acquire others' writes
    }
    __syncthreads();
}

// One kernel, three phases (replaces memset + mark + write = 3 graph nodes):
//  P1: grid-stride float4 zero of the 134 MB output (plain cached stores —
//      NT stores measured slower, r2).
//  P2: deterministic winner per (src,dst) slot = max edge id (matches np/JAX
//      scatter last-write-wins). Marker (e+1) as uint in word 0 of the slot.
//  P3: each edge re-reads the marker (atomicOr(p,0) = device-coherent load);
//      only the winner computes the MLP and writes all 8 words. Word-0 race:
//      a losing duplicate reading word 0 concurrently sees either the
//      winner's marker (w+1 != its own e+1) or the winner's final float,
//      whose bit pattern is flushed away from [1,E] (positive denormals
//      < 1e-40 -> 0.0f) — both correctly lose. Proven in r2-r4.
__global__ __launch_bounds__(TPB, 4) void k_all(
        const int* __restrict__ ei, const float* __restrict__ ea,
        const float* __restrict__ W1, const float* __restrict__ b1,
        const float* __restrict__ W2, const float* __restrict__ b2,
        float* __restrict__ out, unsigned* __restrict__ cnts,
        int E, int N, size_t n4) {
    const unsigned T = NBLK * TPB;
    const unsigned tid = blockIdx.x * TPB + threadIdx.x;

    // Phase 1: zero output (coalesced: lane i writes element tid + k*T).
    {
        float4v z = {0.0f, 0.0f, 0.0f, 0.0f};
        float4v* o4 = (float4v*)out;
        for (size_t i = tid; i < n4; i += T) o4[i] = z;
    }
    grid_barrier(&cnts[0], NBLK);

    // Phase 2: winner marking.
    for (unsigned e = tid; e < (unsigned)E; e += T) {
        size_t slot = (size_t)ei[e] * (size_t)N + (size_t)ei[(size_t)E + e];
        atomicMax((unsigned*)(out + slot * NUM_HEADS), e + 1u);
    }
    grid_barrier(&cnts[1], NBLK);

    // Phase 3: winner writes.
    for (unsigned e = tid; e < (unsigned)E; e += T) {
        size_t slot = (size_t)ei[e] * (size_t)N + (size_t)ei[(size_t)E + e];
        float* p = out + slot * NUM_HEADS;
        unsigned m = atomicOr((unsigned*)p, 0u);   // coherent marker read
        if (m != e + 1u) continue;                 // not the winner
        float o[NUM_HEADS];
        edge_mlp(ea[(size_t)e * EDGE_DIM + 0], ea[(size_t)e * EDGE_DIM + 1],
                 ea[(size_t)e * EDGE_DIM + 2], W1, b1, W2, b2, o);
        unsigned u = __float_as_uint(o[0]);
        if (u >= 1u && u <= (unsigned)E) o[0] = 0.0f;  // flush marker-aliasing denormals
        float4v lo = {o[0], o[1], o[2], o[3]};
        float4v hi = {o[4], o[5], o[6], o[7]};
        *(float4v*)p = lo;          // slot is 32B-aligned
        *(float4v*)(p + 4) = hi;
    }
}

// ---- Fallback (proven round-3 structure) if ws can't hold 2 counters ----
__global__ void k_mark_out(const int* __restrict__ ei, float* __restrict__ out,
                           int E, int N) {
    int e = blockIdx.x * blockDim.x + threadIdx.x;
    if (e >= E) return;
    size_t slot = (size_t)ei[e] * (size_t)N + (size_t)ei[E + e];
    atomicMax((unsigned*)(out + slot * NUM_HEADS), (unsigned)(e + 1));
}

__global__ void k_write_out(const int* __restrict__ ei, const float* __restrict__ ea,
                            const float* __restrict__ W1, const float* __restrict__ b1,
                            const float* __restrict__ W2, const float* __restrict__ b2,
                            float* __restrict__ out, int E, int N) {
    int e = blockIdx.x * blockDim.x + threadIdx.x;
    if (e >= E) return;
    size_t slot = (size_t)ei[e] * (size_t)N + (size_t)ei[E + e];
    float* p = out + slot * NUM_HEADS;
    unsigned m = *(const unsigned*)p;
    if (m != (unsigned)(e + 1)) return;
    float o[NUM_HEADS];
    edge_mlp(ea[e * EDGE_DIM + 0], ea[e * EDGE_DIM + 1], ea[e * EDGE_DIM + 2],
             W1, b1, W2, b2, o);
    unsigned u = __float_as_uint(o[0]);
    if (u >= 1u && u <= (unsigned)E) o[0] = 0.0f;
    float4v lo = {o[0], o[1], o[2], o[3]};
    float4v hi = {o[4], o[5], o[6], o[7]};
    *(float4v*)p = lo;
    *(float4v*)(p + 4) = hi;
}

extern "C" void kernel_launch(void* const* d_in, const int* in_sizes, int n_in,
                              void* d_out, int out_size, void* d_ws, size_t ws_size,
                              hipStream_t stream) {
    const int* ei   = (const int*)d_in[0];    // (2, E) int32
    const float* ea = (const float*)d_in[1];  // (E, 3) f32
    const float* W1 = (const float*)d_in[3];  // (3, 16)
    const float* b1 = (const float*)d_in[4];  // (16,)
    const float* W2 = (const float*)d_in[5];  // (16, 8)
    const float* b2 = (const float*)d_in[6];  // (8,)
    float* out = (float*)d_out;

    const int E = in_sizes[0] / 2;
    const int N = (int)(sqrt((double)(out_size / NUM_HEADS)) + 0.5);
    size_t n4 = (size_t)out_size / 4;

    if (ws_size >= 2 * sizeof(unsigned)) {
        unsigned* cnts = (unsigned*)d_ws;
        // Node 1: zero the two barrier counters (re-zeroed every replay —
        // the memset node is part of the captured graph).
        hipMemsetAsync(cnts, 0, 2 * sizeof(unsigned), stream);
        // Node 2: fused zero -> mark -> write.
        k_all<<<NBLK, TPB, 0, stream>>>(ei, ea, W1, b1, W2, b2, out, cnts,
                                        E, N, n4);
    } else {
        // Fallback: proven round-3 3-node path.
        hipMemsetAsync(d_out, 0, (size_t)out_size * sizeof(float), stream);
        const int blk = 256;
        const int grid = (E + blk - 1) / blk;
        k_mark_out<<<grid, blk, 0, stream>>>(ei, out, E, N);
        k_write_out<<<grid, blk, 0, stream>>>(ei, ea, W1, b1, W2, b2, out, E, N);
    }
}

// Round 8
// 56.834 us; speedup vs baseline: 5.0946x; 1.1811x over previous
//
#include <hip/hip_runtime.h>
#include <math.h>

#define EDGE_DIM 3
#define NUM_HEADS 8
#define HIDDEN 16

typedef float float4v __attribute__((ext_vector_type(4)));

// Per-edge tiny MLP: (3) -> (16) relu -> (8)
__device__ __forceinline__ void edge_mlp(const float a0, const float a1, const float a2,
                                         const float* __restrict__ W1,
                                         const float* __restrict__ b1,
                                         const float* __restrict__ W2,
                                         const float* __restrict__ b2,
                                         float* o /* [NUM_HEADS] */) {
    float h[HIDDEN];
#pragma unroll
    for (int j = 0; j < HIDDEN; ++j) {
        float s = b1[j];
        s += a0 * W1[0 * HIDDEN + j];
        s += a1 * W1[1 * HIDDEN + j];
        s += a2 * W1[2 * HIDDEN + j];
        h[j] = s > 0.0f ? s : 0.0f;
    }
#pragma unroll
    for (int i = 0; i < NUM_HEADS; ++i) {
        float s = b2[i];
#pragma unroll
        for (int j = 0; j < HIDDEN; ++j) s += h[j] * W2[j * NUM_HEADS + i];
        o[i] = s;
    }
}

// Node 1: garbage-tolerant winner marking (winner = max edge id = np/JAX
// last-write-wins). Word 0 of the slot gets tag e+1 via a CAS-max loop that
// treats ANY value outside [1,E] (0xAA poison, zeros, stale flushed floats)
// as "unclaimed". Also records the slot in a dual-rail bitmap in ws:
// claimed iff A&~B — repeated-byte poison gives A&~B==0 (A==B), fresh zeros
// give 0, stale state from a previous identical call gives exactly the
// current claimed set. No initialization of ws is ever needed.
__global__ void k_mark(const int* __restrict__ ei, float* __restrict__ out,
                       unsigned long long* __restrict__ bmA,
                       unsigned long long* __restrict__ bmB,
                       int E, int N) {
    int e = blockIdx.x * blockDim.x + threadIdx.x;
    if (e >= E) return;
    size_t slot = (size_t)ei[e] * (size_t)N + (size_t)ei[E + e];
    unsigned* p = (unsigned*)(out + slot * NUM_HEADS);
    const unsigned my = (unsigned)(e + 1);

    unsigned w = atomicOr(p, 0u);          // coherent read of current word0
    while (true) {
        bool is_tag = (w >= 1u && w <= (unsigned)E);
        if (is_tag && w >= my) break;      // a higher edge owns: lose
        unsigned old = atomicCAS(p, w, my);
        if (old == w) break;               // claimed
        w = old;                           // raced: re-examine actual value
    }
    atomicOr(&bmA[slot >> 6], 1ull << (slot & 63));
    atomicAnd(&bmB[slot >> 6], ~(1ull << (slot & 63)));
}

// Node 2: fused zero+write. One thread per 16B unit (2 units/slot), exact
// cover -> unit-stride fully-coalesced dwordx4 stores. Unclaimed slots are
// written as zeros with NO fetch (the 99.8% streaming case). Claimed slots:
// both lanes of the slot read the word0 tag (the load precedes the store in
// wave program order + data dependency, so the even lane's overwrite of
// word0 cannot race the odd lane's read), verify slot(tag-1)==s, compute the
// MLP, and write their half. o[0] bits are flushed out of [1,E] (positive
// denormals < 1e-39 -> 0.0f) so a stale word0 from this call can never be
// mistaken for a tag by the next call's k_mark.
__global__ __launch_bounds__(256) void k_fill(
        const unsigned long long* __restrict__ bmA,
        const unsigned long long* __restrict__ bmB,
        const int* __restrict__ ei, const float* __restrict__ ea,
        const float* __restrict__ W1, const float* __restrict__ b1,
        const float* __restrict__ W2, const float* __restrict__ b2,
        float4v* __restrict__ out4, int E, int N, size_t nunits) {
    size_t u = (size_t)blockIdx.x * 256 + threadIdx.x;
    if (u >= nunits) return;
    size_t s = u >> 1;                     // slot index
    float4v v = {0.0f, 0.0f, 0.0f, 0.0f};
    unsigned long long bm = bmA[s >> 6] & ~bmB[s >> 6];   // coalesced/broadcast
    if ((bm >> (s & 63)) & 1ull) {
        unsigned t = ((const unsigned*)&out4[s << 1])[0];  // word0 tag
        if (t >= 1u && t <= (unsigned)E) {
            unsigned e = t - 1u;
            size_t es = (size_t)ei[e] * (size_t)N + (size_t)ei[(size_t)E + e];
            if (es == s) {                 // genuine claim (guards garbage)
                float o[NUM_HEADS];
                edge_mlp(ea[(size_t)e * EDGE_DIM + 0], ea[(size_t)e * EDGE_DIM + 1],
                         ea[(size_t)e * EDGE_DIM + 2], W1, b1, W2, b2, o);
                unsigned u0 = __float_as_uint(o[0]);
                if (u0 >= 1u && u0 <= (unsigned)E) o[0] = 0.0f;  // keep word0 out of tag range
                if (u & 1) { v[0] = o[4]; v[1] = o[5]; v[2] = o[6]; v[3] = o[7]; }
                else       { v[0] = o[0]; v[1] = o[1]; v[2] = o[2]; v[3] = o[3]; }
            }
        }
    }
    out4[u] = v;
}

// ---- Fallback (proven round-3 structure, 33.1 us) if ws too small ----
__global__ void k_mark_out(const int* __restrict__ ei, float* __restrict__ out,
                           int E, int N) {
    int e = blockIdx.x * blockDim.x + threadIdx.x;
    if (e >= E) return;
    size_t slot = (size_t)ei[e] * (size_t)N + (size_t)ei[E + e];
    atomicMax((unsigned*)(out + slot * NUM_HEADS), (unsigned)(e + 1));
}

__global__ void k_write_out(const int* __restrict__ ei, const float* __restrict__ ea,
                            const float* __restrict__ W1, const float* __restrict__ b1,
                            const float* __restrict__ W2, const float* __restrict__ b2,
                            float* __restrict__ out, int E, int N) {
    int e = blockIdx.x * blockDim.x + threadIdx.x;
    if (e >= E) return;
    size_t slot = (size_t)ei[e] * (size_t)N + (size_t)ei[E + e];
    float* p = out + slot * NUM_HEADS;
    unsigned m = *(const unsigned*)p;
    if (m != (unsigned)(e + 1)) return;
    float o[NUM_HEADS];
    edge_mlp(ea[e * EDGE_DIM + 0], ea[e * EDGE_DIM + 1], ea[e * EDGE_DIM + 2],
             W1, b1, W2, b2, o);
    unsigned u = __float_as_uint(o[0]);
    if (u >= 1u && u <= (unsigned)E) o[0] = 0.0f;
    float4v lo = {o[0], o[1], o[2], o[3]};
    float4v hi = {o[4], o[5], o[6], o[7]};
    *(float4v*)p = lo;
    *(float4v*)(p + 4) = hi;
}

extern "C" void kernel_launch(void* const* d_in, const int* in_sizes, int n_in,
                              void* d_out, int out_size, void* d_ws, size_t ws_size,
                              hipStream_t stream) {
    const int* ei   = (const int*)d_in[0];    // (2, E) int32
    const float* ea = (const float*)d_in[1];  // (E, 3) f32
    const float* W1 = (const float*)d_in[3];  // (3, 16)
    const float* b1 = (const float*)d_in[4];  // (16,)
    const float* W2 = (const float*)d_in[5];  // (16, 8)
    const float* b2 = (const float*)d_in[6];  // (8,)
    float* out = (float*)d_out;

    const int E = in_sizes[0] / 2;
    const int N = (int)(sqrt((double)(out_size / NUM_HEADS)) + 0.5);
    const size_t nslots = (size_t)N * (size_t)N;
    const size_t nunits = nslots * 2;                 // 16B units
    const size_t nwords = (nslots + 63) / 64;         // bitmap u64 words

    const int blk = 256;
    const int egrid = (E + blk - 1) / blk;

    if (ws_size >= 2 * nwords * sizeof(unsigned long long)) {
        unsigned long long* bmA = (unsigned long long*)d_ws;
        unsigned long long* bmB = bmA + nwords;
        // Node 1: claim + bitmap (no init of anything needed).
        k_mark<<<egrid, blk, 0, stream>>>(ei, out, bmA, bmB, E, N);
        // Node 2: fused zero+payload, single full pass over the output.
        const int fgrid = (int)((nunits + blk - 1) / blk);
        k_fill<<<fgrid, blk, 0, stream>>>(bmA, bmB, ei, ea, W1, b1, W2, b2,
                                          (float4v*)out, E, N, nunits);
    } else {
        // Fallback: proven 3-node round-3 path.
        hipMemsetAsync(d_out, 0, (size_t)out_size * sizeof(float), stream);
        k_mark_out<<<egrid, blk, 0, stream>>>(ei, out, E, N);
        k_write_out<<<egrid, blk, 0, stream>>>(ei, ea, W1, b1, W2, b2, out, E, N);
    }
}

// Round 9
// 53.862 us; speedup vs baseline: 5.3758x; 1.0552x over previous
//
#include <hip/hip_runtime.h>
#include <math.h>

#define EDGE_DIM 3
#define NUM_HEADS 8
#define HIDDEN 16

typedef float float4v __attribute__((ext_vector_type(4)));

// Per-edge tiny MLP: (3) -> (16) relu -> (8)
__device__ __forceinline__ void edge_mlp(const float a0, const float a1, const float a2,
                                         const float* __restrict__ W1,
                                         const float* __restrict__ b1,
                                         const float* __restrict__ W2,
                                         const float* __restrict__ b2,
                                         float* o /* [NUM_HEADS] */) {
    float h[HIDDEN];
#pragma unroll
    for (int j = 0; j < HIDDEN; ++j) {
        float s = b1[j];
        s += a0 * W1[0 * HIDDEN + j];
        s += a1 * W1[1 * HIDDEN + j];
        s += a2 * W1[2 * HIDDEN + j];
        h[j] = s > 0.0f ? s : 0.0f;
    }
#pragma unroll
    for (int i = 0; i < NUM_HEADS; ++i) {
        float s = b2[i];
#pragma unroll
        for (int j = 0; j < HIDDEN; ++j) s += h[j] * W2[j * NUM_HEADS + i];
        o[i] = s;
    }
}

// Node 1: garbage-tolerant winner marking (winner = max edge id = np/JAX
// last-write-wins). Word 0 of the slot gets tag e+1 via a CAS-max loop that
// treats ANY value outside [1,E] (0xAA poison, zeros, stale flushed floats)
// as "unclaimed". Also records the slot in a dual-rail bitmap in ws:
// claimed iff A&~B — any repeated-pattern poison has A==B -> A&~B==0, so no
// ws initialization is ever needed; stale state from a previous identical
// call reproduces exactly the current claimed set.
__global__ void k_mark(const int* __restrict__ ei, float* __restrict__ out,
                       unsigned long long* __restrict__ bmA,
                       unsigned long long* __restrict__ bmB,
                       int E, int N) {
    int e = blockIdx.x * blockDim.x + threadIdx.x;
    if (e >= E) return;
    size_t slot = (size_t)ei[e] * (size_t)N + (size_t)ei[E + e];
    unsigned* p = (unsigned*)(out + slot * NUM_HEADS);
    const unsigned my = (unsigned)(e + 1);

    unsigned w = atomicOr(p, 0u);          // coherent read of current word0
    while (true) {
        bool is_tag = (w >= 1u && w <= (unsigned)E);
        if (is_tag && w >= my) break;      // a higher edge owns: lose
        unsigned old = atomicCAS(p, w, my);
        if (old == w) break;               // claimed
        w = old;                           // raced: re-examine actual value
    }
    atomicOr(&bmA[slot >> 6], 1ull << (slot & 63));
    atomicAnd(&bmB[slot >> 6], ~(1ull << (slot & 63)));
}

// Node 2: fused zero+write, grid-stride (r8 post-mortem: 32768 one-shot
// blocks ran at 2.7 TB/s — workgroup dispatch rate + no ILP; fix is a
// 2048-block grid-stride config like the rocclr fill). One thread per SLOT
// per iteration: wave writes 64 x 32B = 2KB contiguous, 8 iters/thread.
// Unclaimed slots (99.8%): zeros, no fetch beyond one broadcast bitmap word
// per wave. Claimed slots: this thread owns the whole slot, reads the word0
// tag (same-thread program order vs the store — no race), verifies
// slot(tag-1)==s, recomputes the MLP, writes the payload. o[0] bits are
// flushed out of [1,E] (positive denormals < 1e-39 -> 0.0f) so a stale
// word0 can never be mistaken for a tag by the next call's k_mark.
__global__ __launch_bounds__(256) void k_fill(
        const unsigned long long* __restrict__ bmA,
        const unsigned long long* __restrict__ bmB,
        const int* __restrict__ ei, const float* __restrict__ ea,
        const float* __restrict__ W1, const float* __restrict__ b1,
        const float* __restrict__ W2, const float* __restrict__ b2,
        float4v* __restrict__ out4, int E, int N, size_t nslots) {
    const size_t T = (size_t)gridDim.x * blockDim.x;
    const size_t tid = (size_t)blockIdx.x * blockDim.x + threadIdx.x;
    for (size_t s = tid; s < nslots; s += T) {
        float4v lo = {0.0f, 0.0f, 0.0f, 0.0f};
        float4v hi = {0.0f, 0.0f, 0.0f, 0.0f};
        unsigned long long bm = bmA[s >> 6] & ~bmB[s >> 6];  // broadcast in-wave
        if ((bm >> (s & 63)) & 1ull) {
            unsigned t = ((const unsigned*)&out4[s << 1])[0];  // word0 tag
            if (t >= 1u && t <= (unsigned)E) {
                unsigned e = t - 1u;
                size_t es = (size_t)ei[e] * (size_t)N + (size_t)ei[(size_t)E + e];
                if (es == s) {             // genuine claim (guards garbage)
                    float o[NUM_HEADS];
                    edge_mlp(ea[(size_t)e * EDGE_DIM + 0],
                             ea[(size_t)e * EDGE_DIM + 1],
                             ea[(size_t)e * EDGE_DIM + 2],
                             W1, b1, W2, b2, o);
                    unsigned u0 = __float_as_uint(o[0]);
                    if (u0 >= 1u && u0 <= (unsigned)E) o[0] = 0.0f;
                    lo[0] = o[0]; lo[1] = o[1]; lo[2] = o[2]; lo[3] = o[3];
                    hi[0] = o[4]; hi[1] = o[5]; hi[2] = o[6]; hi[3] = o[7];
                }
            }
        }
        out4[(s << 1) + 0] = lo;
        out4[(s << 1) + 1] = hi;
    }
}

// ---- Fallback (proven round-3 structure, 33.1 us) if ws too small ----
__global__ void k_mark_out(const int* __restrict__ ei, float* __restrict__ out,
                           int E, int N) {
    int e = blockIdx.x * blockDim.x + threadIdx.x;
    if (e >= E) return;
    size_t slot = (size_t)ei[e] * (size_t)N + (size_t)ei[E + e];
    atomicMax((unsigned*)(out + slot * NUM_HEADS), (unsigned)(e + 1));
}

__global__ void k_write_out(const int* __restrict__ ei, const float* __restrict__ ea,
                            const float* __restrict__ W1, const float* __restrict__ b1,
                            const float* __restrict__ W2, const float* __restrict__ b2,
                            float* __restrict__ out, int E, int N) {
    int e = blockIdx.x * blockDim.x + threadIdx.x;
    if (e >= E) return;
    size_t slot = (size_t)ei[e] * (size_t)N + (size_t)ei[E + e];
    float* p = out + slot * NUM_HEADS;
    unsigned m = *(const unsigned*)p;
    if (m != (unsigned)(e + 1)) return;
    float o[NUM_HEADS];
    edge_mlp(ea[e * EDGE_DIM + 0], ea[e * EDGE_DIM + 1], ea[e * EDGE_DIM + 2],
             W1, b1, W2, b2, o);
    unsigned u = __float_as_uint(o[0]);
    if (u >= 1u && u <= (unsigned)E) o[0] = 0.0f;
    float4v lo = {o[0], o[1], o[2], o[3]};
    float4v hi = {o[4], o[5], o[6], o[7]};
    *(float4v*)p = lo;
    *(float4v*)(p + 4) = hi;
}

extern "C" void kernel_launch(void* const* d_in, const int* in_sizes, int n_in,
                              void* d_out, int out_size, void* d_ws, size_t ws_size,
                              hipStream_t stream) {
    const int* ei   = (const int*)d_in[0];    // (2, E) int32
    const float* ea = (const float*)d_in[1];  // (E, 3) f32
    const float* W1 = (const float*)d_in[3];  // (3, 16)
    const float* b1 = (const float*)d_in[4];  // (16,)
    const float* W2 = (const float*)d_in[5];  // (16, 8)
    const float* b2 = (const float*)d_in[6];  // (8,)
    float* out = (float*)d_out;

    const int E = in_sizes[0] / 2;
    const int N = (int)(sqrt((double)(out_size / NUM_HEADS)) + 0.5);
    const size_t nslots = (size_t)N * (size_t)N;
    const size_t nwords = (nslots + 63) / 64;         // bitmap u64 words

    const int blk = 256;
    const int egrid = (E + blk - 1) / blk;

    if (ws_size >= 2 * nwords * sizeof(unsigned long long)) {
        unsigned long long* bmA = (unsigned long long*)d_ws;
        unsigned long long* bmB = bmA + nwords;
        // Node 1: claim + bitmap (no init of anything needed).
        k_mark<<<egrid, blk, 0, stream>>>(ei, out, bmA, bmB, E, N);
        // Node 2: fused zero+payload, single grid-stride pass over the output.
        k_fill<<<2048, blk, 0, stream>>>(bmA, bmB, ei, ea, W1, b1, W2, b2,
                                         (float4v*)out, E, N, nslots);
    } else {
        // Fallback: proven 3-node round-3 path.
        hipMemsetAsync(d_out, 0, (size_t)out_size * sizeof(float), stream);
        k_mark_out<<<egrid, blk, 0, stream>>>(ei, out, E, N);
        k_write_out<<<egrid, blk, 0, stream>>>(ei, ea, W1, b1, W2, b2, out, E, N);
    }
}